// Round 20
// baseline (211.058 us; speedup 1.0000x reference)
//
#include <hip/hip_runtime.h>
#include <hip/hip_bf16.h>
#include <cstdint>
#include <cstddef>
#include <type_traits>

#define HID 1024
#define HEADS 8
#define HDIM 128
#define SEQ 4096
#define BATCH 2

typedef float f32x4 __attribute__((ext_vector_type(4)));
typedef float f32x16 __attribute__((ext_vector_type(16)));
typedef short bf16x8 __attribute__((ext_vector_type(8)));
typedef unsigned short u16x8 __attribute__((ext_vector_type(8)));

typedef bf16x8 __attribute__((may_alias)) bf16x8_a;
typedef u16x8  __attribute__((may_alias)) u16x8_a;
typedef float4 __attribute__((may_alias)) float4_a;
typedef unsigned int __attribute__((may_alias)) u32_a;

__device__ __forceinline__ unsigned short f2bf(float f) {
    union { float f; unsigned int u; } v; v.f = f;
    unsigned int u = v.u;
    unsigned int r = (u + 0x7FFFu + ((u >> 16) & 1u)) >> 16;
    return (unsigned short)r;
}
__device__ __forceinline__ float bf2f(unsigned short h) {
    union { unsigned int u; float f; } v; v.u = ((unsigned int)h) << 16;
    return v.f;
}

__device__ __forceinline__ void plane_swap(unsigned int& x, unsigned int& y) {
    asm("v_permlane32_swap_b32 %0, %1" : "+v"(x), "+v"(y));
}
__device__ __forceinline__ unsigned int cvt_pk(float lo, float hi) {
    unsigned int r;
    asm("v_cvt_pk_bf16_f32 %0, %1, %2" : "=v"(r) : "v"(lo), "v"(hi));
    return r;
}
__device__ __forceinline__ bf16x8 pack4(unsigned int a, unsigned int b,
                                        unsigned int c, unsigned int d) {
    union { unsigned int u[4]; bf16x8 v; } t;
    t.u[0] = a; t.u[1] = b; t.u[2] = c; t.u[3] = d;
    return t.v;
}
__device__ __forceinline__ void g2lds16(const unsigned short* g, unsigned short* l) {
    __builtin_amdgcn_global_load_lds(
        (const __attribute__((address_space(1))) void*)g,
        (__attribute__((address_space(3))) void*)l, 16, 0, 0);
}

// f32 -> bf16 bulk convert, 8 elems/thread
__global__ __launch_bounds__(256)
void cvt_kernel(const float* __restrict__ X, unsigned short* __restrict__ Y)
{
    int i = (blockIdx.x * 256 + threadIdx.x) * 8;
    float4 d0 = *(const float4_a*)&X[i];
    float4 d1 = *(const float4_a*)&X[i + 4];
    u16x8 t;
    t[0] = f2bf(d0.x); t[1] = f2bf(d0.y); t[2] = f2bf(d0.z); t[3] = f2bf(d0.w);
    t[4] = f2bf(d1.x); t[5] = f2bf(d1.y); t[6] = f2bf(d1.z); t[7] = f2bf(d1.w);
    *(u16x8_a*)&Y[i] = t;
}

// 4 weight matrices (each HID*HID f32) -> contiguous bf16 at Y.
__global__ __launch_bounds__(256)
void cvtw_kernel(const float* __restrict__ w0, const float* __restrict__ w1,
                 const float* __restrict__ w2, const float* __restrict__ w3,
                 unsigned short* __restrict__ Y)
{
    const int WSZ8 = (HID * HID) / 8;               // 131072
    int c = blockIdx.x * 256 + threadIdx.x;
    int quarter = c >> 17;
    int idx = (c & (WSZ8 - 1)) * 8;
    const float* w = quarter == 0 ? w0 : quarter == 1 ? w1 : quarter == 2 ? w2 : w3;
    float4 d0 = *(const float4_a*)&w[idx];
    float4 d1 = *(const float4_a*)&w[idx + 4];
    u16x8 t;
    t[0] = f2bf(d0.x); t[1] = f2bf(d0.y); t[2] = f2bf(d0.z); t[3] = f2bf(d0.w);
    t[4] = f2bf(d1.x); t[5] = f2bf(d1.y); t[6] = f2bf(d1.z); t[7] = f2bf(d1.w);
    *(u16x8_a*)&Y[(size_t)quarter * HID * HID + idx] = t;
}

// Primary GEMM: swizzled global_load_lds staging (rule #21 / T2), bf16 ops.
// XCD-aware block swizzle (T1): each XCD gets a contiguous chunk of the grid
// so consecutive N-tiles (sharing the A panel) stay on one XCD's L2.
template<typename OutT>
__global__ __launch_bounds__(256)
void gemm_swz(const unsigned short* __restrict__ A, const unsigned short* __restrict__ B,
              OutT* __restrict__ C, int M, int N, int K, int lda)
{
    __shared__ __align__(16) unsigned short Al[128][64];
    __shared__ __align__(16) unsigned short Bl[128][64];
    const int tid  = threadIdx.x;
    const int lane = tid & 63;
    const int w    = tid >> 6;
    const int wr   = w >> 1, wc = w & 1;
    const int l16  = lane & 15, l4 = lane >> 4;
    // XCD swizzle (nwg divisible by 8 for both call sites)
    const int nwg  = gridDim.x * gridDim.y;
    const int id   = blockIdx.y * gridDim.x + blockIdx.x;
    const int swz  = (id & 7) * (nwg >> 3) + (id >> 3);
    const int bx   = swz % gridDim.x, by = swz / gridDim.x;
    const int tm   = by * 128, tn = bx * 128;
    const int srow  = lane >> 3;
    const int sslot = (lane & 7) ^ srow;

    f32x4 acc[4][4] = {};

    for (int ko = 0; ko < K; ko += 64) {
        __syncthreads();
#pragma unroll
        for (int it = 0; it < 4; ++it) {
            int ca = w * 4 + it;
            int row = ca * 8 + srow;
            g2lds16(&A[(size_t)(tm + row) * lda + ko + sslot * 8], &Al[ca * 8][0]);
            g2lds16(&B[(size_t)(tn + row) * K   + ko + sslot * 8], &Bl[ca * 8][0]);
        }
        __syncthreads();
#pragma unroll
        for (int kk = 0; kk < 2; ++kk) {
            const int rslot = (kk * 4 + l4) ^ (l16 & 7);
            bf16x8 af[4], bfr[4];
#pragma unroll
            for (int i = 0; i < 4; ++i)
                af[i] = *(const bf16x8_a*)&Al[wr*64 + i*16 + l16][rslot * 8];
#pragma unroll
            for (int j = 0; j < 4; ++j)
                bfr[j] = *(const bf16x8_a*)&Bl[wc*64 + j*16 + l16][rslot * 8];
#pragma unroll
            for (int i = 0; i < 4; ++i)
#pragma unroll
                for (int j = 0; j < 4; ++j)
                    acc[i][j] = __builtin_amdgcn_mfma_f32_16x16x32_bf16(af[i], bfr[j], acc[i][j], 0, 0, 0);
        }
    }
#pragma unroll
    for (int i = 0; i < 4; ++i)
#pragma unroll
        for (int j = 0; j < 4; ++j)
#pragma unroll
            for (int r = 0; r < 4; ++r) {
                int row = tm + wr*64 + i*16 + l4*4 + r;
                int col = tn + wc*64 + j*16 + l16;
                if constexpr (std::is_same<OutT, float>::value)
                    C[(size_t)row * N + col] = acc[i][j][r];
                else
                    C[(size_t)row * N + col] = f2bf(acc[i][j][r]);
            }
}

// Fallback GEMM (reg-staged padded LDS, f32 or bf16 operands).
template<bool A_BF16, bool B_BF16, typename OutT>
__global__ __launch_bounds__(256)
void gemm_bt(const void* __restrict__ Av, const void* __restrict__ Bv,
             OutT* __restrict__ C, int M, int N, int K, int lda)
{
    __shared__ __align__(16) unsigned short Al[128][72];
    __shared__ __align__(16) unsigned short Bl[128][72];
    const int tid  = threadIdx.x;
    const int lane = tid & 63;
    const int w    = tid >> 6;
    const int wr   = w >> 1, wc = w & 1;
    const int l16  = lane & 15, l4 = lane >> 4;
    const int tm   = blockIdx.y * 128, tn = blockIdx.x * 128;

    f32x4 acc[4][4] = {};

    for (int ko = 0; ko < K; ko += 64) {
        __syncthreads();
#pragma unroll
        for (int it = 0; it < 4; ++it) {
            int c = tid + 256 * it;
            int row = c >> 3, col0 = (c & 7) * 8;
            if constexpr (A_BF16) {
                const unsigned short* A = (const unsigned short*)Av;
                *(u16x8_a*)&Al[row][col0] =
                    *(const u16x8_a*)&A[(size_t)(tm + row) * lda + ko + col0];
            } else {
                const float* A = (const float*)Av;
                const float* p = &A[(size_t)(tm + row) * lda + ko + col0];
                float4 d0 = *(const float4_a*)p;
                float4 d1 = *(const float4_a*)(p + 4);
                u16x8 t;
                t[0] = f2bf(d0.x); t[1] = f2bf(d0.y); t[2] = f2bf(d0.z); t[3] = f2bf(d0.w);
                t[4] = f2bf(d1.x); t[5] = f2bf(d1.y); t[6] = f2bf(d1.z); t[7] = f2bf(d1.w);
                *(u16x8_a*)&Al[row][col0] = t;
            }
            if constexpr (B_BF16) {
                const unsigned short* B = (const unsigned short*)Bv;
                *(u16x8_a*)&Bl[row][col0] =
                    *(const u16x8_a*)&B[(size_t)(tn + row) * K + ko + col0];
            } else {
                const float* B = (const float*)Bv;
                const float* p = &B[(size_t)(tn + row) * K + ko + col0];
                float4 d0 = *(const float4_a*)p;
                float4 d1 = *(const float4_a*)(p + 4);
                u16x8 t;
                t[0] = f2bf(d0.x); t[1] = f2bf(d0.y); t[2] = f2bf(d0.z); t[3] = f2bf(d0.w);
                t[4] = f2bf(d1.x); t[5] = f2bf(d1.y); t[6] = f2bf(d1.z); t[7] = f2bf(d1.w);
                *(u16x8_a*)&Bl[row][col0] = t;
            }
        }
        __syncthreads();
#pragma unroll
        for (int kk = 0; kk < 2; ++kk) {
            bf16x8 af[4], bfr[4];
#pragma unroll
            for (int i = 0; i < 4; ++i)
                af[i] = *(const bf16x8_a*)&Al[wr*64 + i*16 + l16][kk*32 + l4*8];
#pragma unroll
            for (int j = 0; j < 4; ++j)
                bfr[j] = *(const bf16x8_a*)&Bl[wc*64 + j*16 + l16][kk*32 + l4*8];
#pragma unroll
            for (int i = 0; i < 4; ++i)
#pragma unroll
                for (int j = 0; j < 4; ++j)
                    acc[i][j] = __builtin_amdgcn_mfma_f32_16x16x32_bf16(af[i], bfr[j], acc[i][j], 0, 0, 0);
        }
    }
#pragma unroll
    for (int i = 0; i < 4; ++i)
#pragma unroll
        for (int j = 0; j < 4; ++j)
#pragma unroll
            for (int r = 0; r < 4; ++r) {
                int row = tm + wr*64 + i*16 + l4*4 + r;
                int col = tn + wc*64 + j*16 + l16;
                if constexpr (std::is_same<OutT, float>::value)
                    C[(size_t)row * N + col] = acc[i][j][r];
                else
                    C[(size_t)row * N + col] = f2bf(acc[i][j][r]);
            }
}

// In-place RoPE, trig-deduplicated: thread = (token, d-chunk), sincos once,
// applied across NH head-slots. Row stride RS. grid = B*SEQ*16/256.
template<int NH>
__global__ __launch_bounds__(256)
void rope_kernel(unsigned short* __restrict__ X, const int* __restrict__ pos_ids, int RS)
{
    int c = blockIdx.x * 256 + threadIdx.x;
    int d0 = (c & 15) * 8;
    int l  = (c >> 4) & 4095;
    int b  = c >> 16;
    int pos = pos_ids[b * SEQ + l];
    float sth[4], cth[4];
#pragma unroll
    for (int j = 0; j < 4; ++j) {
        int i = (d0 >> 1) + j;
        float invf = powf(10000.0f, -(float)i * (1.0f / 64.0f));
        float ang = (float)pos * invf;
        sincosf(ang, &sth[j], &cth[j]);
    }
    size_t base = (size_t)(b * SEQ + l) * RS + d0;
#pragma unroll
    for (int h = 0; h < NH; ++h) {
        u16x8 d = *(const u16x8_a*)&X[base + h * HDIM];
#pragma unroll
        for (int j = 0; j < 4; ++j) {
            float x0 = bf2f(d[2*j]), x1 = bf2f(d[2*j+1]);
            d[2*j]   = f2bf(x0 * cth[j] - x1 * sth[j]);
            d[2*j+1] = f2bf(x0 * sth[j] + x1 * cth[j]);
        }
        *(u16x8_a*)&X[base + h * HDIM] = d;
    }
}

// Flash attention: BLOCK-causal + segment mask + skip + uniform-mask fast
// path; swapped QK^T; in-reg P; double-buffered LDS, one barrier per tile.
// r20: staging write moved between QK^T and exp (overlaps VALU phase);
// s_setprio(1) around MFMA clusters (T5); exp2 with folded log2e scale.
// O aliases Q (in-place). launch_bounds(256,2): must not spill (r14 lesson).
__global__ __launch_bounds__(256, 2)
void attn_kernel(const unsigned short* Q,
                 const unsigned short* K,
                 const unsigned short* V,
                 const int* __restrict__ seg,
                 unsigned short* O, int RS)
{
    __shared__ __align__(16) unsigned short Kl[2][64][136];
    __shared__ __align__(16) unsigned short Vt[2][128][72];

    const int tid  = threadIdx.x;
    const int lane = tid & 63;
    const int l32  = lane & 31, hi = lane >> 5;
    const int w    = tid >> 6;
    const int qt = (SEQ / 128 - 1) - blockIdx.x;
    const int h  = blockIdx.y;
    const int b  = blockIdx.z;
    const int qg0 = qt * 128 + w * 32;
    const int hoff = h * HDIM;

    bf16x8 qf[8];
    {
        size_t base = (size_t)(b * SEQ + qg0 + l32) * RS + hoff;
#pragma unroll
        for (int kk = 0; kk < 8; ++kk)
            qf[kk] = *(const bf16x8_a*)&Q[base + kk*16 + hi*8];
    }

    f32x16 acco0 = {}, acco1 = {}, acco2 = {}, acco3 = {};
    float lsum = 0.f;

    const int nkt = ((qt >> 4) + 1) * 32;

    int lo = 0, hb = SEQ;
    while (lo < hb) { int mid = (lo + hb) >> 1; if (seg[b * SEQ + mid] == 0) lo = mid + 1; else hb = mid; }
    const int boundary = lo;
    const bool blk_seg1 = (seg[b * SEQ + qt * 128] == 1);
    const bool blk_seg0 = (seg[b * SEQ + qt * 128 + 127] == 0);
    const bool mixed = !blk_seg0 && !blk_seg1;
    int kstart = 0, kend = nkt;
    if (blk_seg1) kstart = boundary >> 6;
    if (blk_seg0) {
        int ke = (boundary + 63) >> 6;
        kend = ke < nkt ? ke : nkt;
    }
    const bool qlt = (qg0 + l32) < boundary;

    const int kp = tid & 31, db = tid >> 5;
    const float sc2 = 0.08838834764831845f * 1.4426950408889634f;  // 1/sqrt(128)*log2(e)

    // ---- prefetch regs for tile kstart ----
    u16x8 kreg[4], v0a, v0b, v1a, v1b;
    {
        const int kb = kstart * 64;
#pragma unroll
        for (int it = 0; it < 4; ++it) {
            int c = tid + 256 * it;
            kreg[it] = *(const u16x8_a*)&K[(size_t)(b * SEQ + kb + (c >> 4)) * RS + hoff + (c & 15) * 8];
        }
        size_t vb0 = (size_t)(b * SEQ + kb + 2 * kp) * RS + hoff + db * 16;
        size_t vb1 = (size_t)(b * SEQ + kb + 2 * kp + 1) * RS + hoff + db * 16;
        v0a = *(const u16x8_a*)&V[vb0];     v0b = *(const u16x8_a*)&V[vb0 + 8];
        v1a = *(const u16x8_a*)&V[vb1];     v1b = *(const u16x8_a*)&V[vb1 + 8];
    }
    // ---- prologue: write tile kstart -> buffer 0; issue loads kstart+1 ----
#pragma unroll
    for (int it = 0; it < 4; ++it) {
        int c = tid + 256 * it;
        *(u16x8_a*)&Kl[0][c >> 4][(c & 15) * 8] = kreg[it];
    }
#pragma unroll
    for (int j = 0; j < 8; ++j) {
        *(u32_a*)&Vt[0][db * 16 + j][2 * kp] =
            (unsigned int)(unsigned short)v0a[j] | ((unsigned int)(unsigned short)v1a[j] << 16);
        *(u32_a*)&Vt[0][db * 16 + 8 + j][2 * kp] =
            (unsigned int)(unsigned short)v0b[j] | ((unsigned int)(unsigned short)v1b[j] << 16);
    }
    if (kstart + 1 < kend) {
        const int kb2 = (kstart + 1) * 64;
#pragma unroll
        for (int it = 0; it < 4; ++it) {
            int c = tid + 256 * it;
            kreg[it] = *(const u16x8_a*)&K[(size_t)(b * SEQ + kb2 + (c >> 4)) * RS + hoff + (c & 15) * 8];
        }
        size_t vb0 = (size_t)(b * SEQ + kb2 + 2 * kp) * RS + hoff + db * 16;
        size_t vb1 = (size_t)(b * SEQ + kb2 + 2 * kp + 1) * RS + hoff + db * 16;
        v0a = *(const u16x8_a*)&V[vb0];     v0b = *(const u16x8_a*)&V[vb0 + 8];
        v1a = *(const u16x8_a*)&V[vb1];     v1b = *(const u16x8_a*)&V[vb1 + 8];
    }
    __syncthreads();

    int buf = 0;
    for (int kt = kstart; kt < kend; ++kt) {
        const int kb = kt * 64;
        const bool have_next = (kt + 1 < kend);

        // ---- QK^T(t) from LDS[buf] (setprio around MFMA cluster) ----
        f32x16 a0 = {}, a1 = {};
        __builtin_amdgcn_s_setprio(1);
#pragma unroll
        for (int kk = 0; kk < 8; ++kk) {
            bf16x8 k0 = *(const bf16x8_a*)&Kl[buf][     l32][kk*16 + hi*8];
            bf16x8 k1 = *(const bf16x8_a*)&Kl[buf][32 + l32][kk*16 + hi*8];
            a0 = __builtin_amdgcn_mfma_f32_32x32x16_bf16(k0, qf[kk], a0, 0, 0, 0);
            a1 = __builtin_amdgcn_mfma_f32_32x32x16_bf16(k1, qf[kk], a1, 0, 0, 0);
        }
        __builtin_amdgcn_s_setprio(0);

        // ---- write tile t+1 -> LDS[buf^1] (overlaps the exp VALU phase) ----
        if (have_next) {
            const int nb = buf ^ 1;
#pragma unroll
            for (int it = 0; it < 4; ++it) {
                int c = tid + 256 * it;
                *(u16x8_a*)&Kl[nb][c >> 4][(c & 15) * 8] = kreg[it];
            }
#pragma unroll
            for (int j = 0; j < 8; ++j) {
                *(u32_a*)&Vt[nb][db * 16 + j][2 * kp] =
                    (unsigned int)(unsigned short)v0a[j] | ((unsigned int)(unsigned short)v1a[j] << 16);
                *(u32_a*)&Vt[nb][db * 16 + 8 + j][2 * kp] =
                    (unsigned int)(unsigned short)v0b[j] | ((unsigned int)(unsigned short)v1b[j] << 16);
            }
        }

        // ---- exp + pack (exp2 with folded scale) ----
        unsigned int pk0[8], pk1[8];
        const bool need_mask = mixed || (kb < boundary && kb + 64 > boundary);
        if (need_mask) {
            const int kb0 = kb + 4 * hi, kb1 = kb + 32 + 4 * hi;
#pragma unroll
            for (int i = 0; i < 8; ++i) {
                int r0 = 2 * i;
                int off = (r0 & 3) + 8 * (r0 >> 2);
                float p0 = ((kb0 + off     < boundary) == qlt) ? exp2f(a0[r0]     * sc2) : 0.0f;
                float p1 = ((kb0 + off + 1 < boundary) == qlt) ? exp2f(a0[r0 + 1] * sc2) : 0.0f;
                float q0 = ((kb1 + off     < boundary) == qlt) ? exp2f(a1[r0]     * sc2) : 0.0f;
                float q1 = ((kb1 + off + 1 < boundary) == qlt) ? exp2f(a1[r0 + 1] * sc2) : 0.0f;
                lsum += (p0 + p1) + (q0 + q1);
                pk0[i] = cvt_pk(p0, p1);
                pk1[i] = cvt_pk(q0, q1);
            }
        } else {
#pragma unroll
            for (int i = 0; i < 8; ++i) {
                int r0 = 2 * i;
                float p0 = exp2f(a0[r0]     * sc2);
                float p1 = exp2f(a0[r0 + 1] * sc2);
                float q0 = exp2f(a1[r0]     * sc2);
                float q1 = exp2f(a1[r0 + 1] * sc2);
                lsum += (p0 + p1) + (q0 + q1);
                pk0[i] = cvt_pk(p0, p1);
                pk1[i] = cvt_pk(q0, q1);
            }
        }
        plane_swap(pk0[0], pk0[2]); plane_swap(pk0[1], pk0[3]);
        plane_swap(pk0[4], pk0[6]); plane_swap(pk0[5], pk0[7]);
        plane_swap(pk1[0], pk1[2]); plane_swap(pk1[1], pk1[3]);
        plane_swap(pk1[4], pk1[6]); plane_swap(pk1[5], pk1[7]);
        bf16x8 pf[4];
        pf[0] = pack4(pk0[0], pk0[1], pk0[2], pk0[3]);
        pf[1] = pack4(pk0[4], pk0[5], pk0[6], pk0[7]);
        pf[2] = pack4(pk1[0], pk1[1], pk1[2], pk1[3]);
        pf[3] = pack4(pk1[4], pk1[5], pk1[6], pk1[7]);

        // ---- PV(t) from LDS[buf] (setprio) ----
        __builtin_amdgcn_s_setprio(1);
#pragma unroll
        for (int ks = 0; ks < 4; ++ks) {
            bf16x8 vf0 = *(const bf16x8_a*)&Vt[buf][      l32][ks*16 + hi*8];
            bf16x8 vf1 = *(const bf16x8_a*)&Vt[buf][32  + l32][ks*16 + hi*8];
            bf16x8 vf2 = *(const bf16x8_a*)&Vt[buf][64  + l32][ks*16 + hi*8];
            bf16x8 vf3 = *(const bf16x8_a*)&Vt[buf][96  + l32][ks*16 + hi*8];
            acco0 = __builtin_amdgcn_mfma_f32_32x32x16_bf16(pf[ks], vf0, acco0, 0, 0, 0);
            acco1 = __builtin_amdgcn_mfma_f32_32x32x16_bf16(pf[ks], vf1, acco1, 0, 0, 0);
            acco2 = __builtin_amdgcn_mfma_f32_32x32x16_bf16(pf[ks], vf2, acco2, 0, 0, 0);
            acco3 = __builtin_amdgcn_mfma_f32_32x32x16_bf16(pf[ks], vf3, acco3, 0, 0, 0);
        }
        __builtin_amdgcn_s_setprio(0);

        // ---- issue loads for t+2; one barrier per tile ----
        if (have_next) {
            if (kt + 2 < kend) {
                const int kb2 = (kt + 2) * 64;
#pragma unroll
                for (int it = 0; it < 4; ++it) {
                    int c = tid + 256 * it;
                    kreg[it] = *(const u16x8_a*)&K[(size_t)(b * SEQ + kb2 + (c >> 4)) * RS + hoff + (c & 15) * 8];
                }
                size_t vb0 = (size_t)(b * SEQ + kb2 + 2 * kp) * RS + hoff + db * 16;
                size_t vb1 = (size_t)(b * SEQ + kb2 + 2 * kp + 1) * RS + hoff + db * 16;
                v0a = *(const u16x8_a*)&V[vb0];     v0b = *(const u16x8_a*)&V[vb0 + 8];
                v1a = *(const u16x8_a*)&V[vb1];     v1b = *(const u16x8_a*)&V[vb1 + 8];
            }
            __syncthreads();
        }
        buf ^= 1;
    }

    // ---- epilogue ----
    float tot = lsum + __shfl_xor(lsum, 32, 64);
#pragma unroll
    for (int r = 0; r < 16; ++r) {
        int qrow = (r & 3) + 8 * (r >> 2) + 4 * hi;
        float inv = 1.0f / __shfl(tot, qrow, 64);
        size_t base = (size_t)(b * SEQ + qg0 + qrow) * RS + hoff;
        O[base +       l32] = f2bf(acco0[r] * inv);
        O[base +  32 + l32] = f2bf(acco1[r] * inv);
        O[base +  64 + l32] = f2bf(acco2[r] * inv);
        O[base +  96 + l32] = f2bf(acco3[r] * inv);
    }
}

extern "C" void kernel_launch(void* const* d_in, const int* in_sizes, int n_in,
                              void* d_out, int out_size, void* d_ws, size_t ws_size,
                              hipStream_t stream)
{
    const float* X  = (const float*)d_in[0];
    const float* wq = (const float*)d_in[1];
    const float* wk = (const float*)d_in[2];
    const float* wv = (const float*)d_in[3];
    const float* wo = (const float*)d_in[4];
    const int* seg = (const int*)d_in[n_in - 2];
    const int* pos = (const int*)d_in[n_in - 1];
    float* out = (float*)d_out;

    const size_t NTOK = (size_t)BATCH * SEQ;        // 8192
    const size_t MAT  = NTOK * HID;                 // 8.39M elems
    const size_t WSZ  = (size_t)HID * HID;          // 1.05M elems

    if (ws_size >= (4 * MAT + 4 * WSZ) * sizeof(unsigned short)) {
        unsigned short* QKVb = (unsigned short*)d_ws;              // 3*MAT
        unsigned short* Xb   = QKVb + 3 * MAT;                     // MAT
        unsigned short* Wb   = Xb + MAT;                           // 4*WSZ
        unsigned short* Wob  = Wb + 3 * WSZ;

        cvt_kernel<<<(int)(MAT / (256 * 8)), 256, 0, stream>>>(X, Xb);
        cvtw_kernel<<<(int)(4 * WSZ / (256 * 8)), 256, 0, stream>>>(wq, wk, wv, wo, Wb);

        dim3 gq(3 * HID / 128, (int)(NTOK / 128));   // (24, 64) -> 1536 blocks
        gemm_swz<unsigned short><<<gq, 256, 0, stream>>>(
            Xb, Wb, QKVb, (int)NTOK, 3 * HID, HID, HID);

        rope_kernel<16><<<(BATCH * SEQ * 16) / 256, 256, 0, stream>>>(QKVb, pos, 3 * HID);

        dim3 ga(SEQ / 128, HEADS, BATCH);
        attn_kernel<<<ga, 256, 0, stream>>>(QKVb, QKVb + HID, QKVb + 2 * HID, seg,
                                            QKVb /* in-place into Q slots */, 3 * HID);

        dim3 go(HID / 128, (int)(NTOK / 128));       // (8, 64) -> 512 blocks
        gemm_swz<float><<<go, 256, 0, stream>>>(
            QKVb, Wob, out, (int)NTOK, HID, HID, 3 * HID);
    } else {
        unsigned short* Qb = (unsigned short*)d_ws;
        unsigned short* Kb = Qb + MAT;
        unsigned short* Vb = Kb + MAT;

        dim3 gg(HID / 128, (int)(NTOK / 128));
        gemm_bt<false, false, unsigned short><<<gg, 256, 0, stream>>>(
            (const void*)X, (const void*)wq, Qb, (int)NTOK, HID, HID, HID);
        gemm_bt<false, false, unsigned short><<<gg, 256, 0, stream>>>(
            (const void*)X, (const void*)wk, Kb, (int)NTOK, HID, HID, HID);
        gemm_bt<false, false, unsigned short><<<gg, 256, 0, stream>>>(
            (const void*)X, (const void*)wv, Vb, (int)NTOK, HID, HID, HID);

        rope_kernel<8><<<(BATCH * SEQ * 16) / 256, 256, 0, stream>>>(Qb, pos, HID);
        rope_kernel<8><<<(BATCH * SEQ * 16) / 256, 256, 0, stream>>>(Kb, pos, HID);

        dim3 ga(SEQ / 128, HEADS, BATCH);
        attn_kernel<<<ga, 256, 0, stream>>>(Qb, Kb, Vb, seg, Qb, HID);

        gemm_bt<true, false, float><<<gg, 256, 0, stream>>>(
            (const void*)Qb, (const void*)wo, out, (int)NTOK, HID, HID, HID);
    }
}

// Round 21
// 202.945 us; speedup vs baseline: 1.0400x; 1.0400x over previous
//
#include <hip/hip_runtime.h>
#include <hip/hip_bf16.h>
#include <cstdint>
#include <cstddef>
#include <type_traits>

#define HID 1024
#define HEADS 8
#define HDIM 128
#define SEQ 4096
#define BATCH 2

typedef float f32x4 __attribute__((ext_vector_type(4)));
typedef float f32x16 __attribute__((ext_vector_type(16)));
typedef short bf16x8 __attribute__((ext_vector_type(8)));
typedef unsigned short u16x8 __attribute__((ext_vector_type(8)));

typedef bf16x8 __attribute__((may_alias)) bf16x8_a;
typedef u16x8  __attribute__((may_alias)) u16x8_a;
typedef float4 __attribute__((may_alias)) float4_a;
typedef unsigned int __attribute__((may_alias)) u32_a;

__device__ __forceinline__ unsigned short f2bf(float f) {
    union { float f; unsigned int u; } v; v.f = f;
    unsigned int u = v.u;
    unsigned int r = (u + 0x7FFFu + ((u >> 16) & 1u)) >> 16;
    return (unsigned short)r;
}
__device__ __forceinline__ float bf2f(unsigned short h) {
    union { unsigned int u; float f; } v; v.u = ((unsigned int)h) << 16;
    return v.f;
}

__device__ __forceinline__ void plane_swap(unsigned int& x, unsigned int& y) {
    asm("v_permlane32_swap_b32 %0, %1" : "+v"(x), "+v"(y));
}
__device__ __forceinline__ unsigned int cvt_pk(float lo, float hi) {
    unsigned int r;
    asm("v_cvt_pk_bf16_f32 %0, %1, %2" : "=v"(r) : "v"(lo), "v"(hi));
    return r;
}
__device__ __forceinline__ bf16x8 pack4(unsigned int a, unsigned int b,
                                        unsigned int c, unsigned int d) {
    union { unsigned int u[4]; bf16x8 v; } t;
    t.u[0] = a; t.u[1] = b; t.u[2] = c; t.u[3] = d;
    return t.v;
}
__device__ __forceinline__ void g2lds16(const unsigned short* g, unsigned short* l) {
    __builtin_amdgcn_global_load_lds(
        (const __attribute__((address_space(1))) void*)g,
        (__attribute__((address_space(3))) void*)l, 16, 0, 0);
}

// f32 -> bf16 bulk convert, 8 elems/thread
__global__ __launch_bounds__(256)
void cvt_kernel(const float* __restrict__ X, unsigned short* __restrict__ Y)
{
    int i = (blockIdx.x * 256 + threadIdx.x) * 8;
    float4 d0 = *(const float4_a*)&X[i];
    float4 d1 = *(const float4_a*)&X[i + 4];
    u16x8 t;
    t[0] = f2bf(d0.x); t[1] = f2bf(d0.y); t[2] = f2bf(d0.z); t[3] = f2bf(d0.w);
    t[4] = f2bf(d1.x); t[5] = f2bf(d1.y); t[6] = f2bf(d1.z); t[7] = f2bf(d1.w);
    *(u16x8_a*)&Y[i] = t;
}

// 4 weight matrices (each HID*HID f32) -> contiguous bf16 at Y.
__global__ __launch_bounds__(256)
void cvtw_kernel(const float* __restrict__ w0, const float* __restrict__ w1,
                 const float* __restrict__ w2, const float* __restrict__ w3,
                 unsigned short* __restrict__ Y)
{
    const int WSZ8 = (HID * HID) / 8;               // 131072
    int c = blockIdx.x * 256 + threadIdx.x;
    int quarter = c >> 17;
    int idx = (c & (WSZ8 - 1)) * 8;
    const float* w = quarter == 0 ? w0 : quarter == 1 ? w1 : quarter == 2 ? w2 : w3;
    float4 d0 = *(const float4_a*)&w[idx];
    float4 d1 = *(const float4_a*)&w[idx + 4];
    u16x8 t;
    t[0] = f2bf(d0.x); t[1] = f2bf(d0.y); t[2] = f2bf(d0.z); t[3] = f2bf(d0.w);
    t[4] = f2bf(d1.x); t[5] = f2bf(d1.y); t[6] = f2bf(d1.z); t[7] = f2bf(d1.w);
    *(u16x8_a*)&Y[(size_t)quarter * HID * HID + idx] = t;
}

// Primary GEMM: swizzled global_load_lds staging (rule #21 / T2), bf16 ops.
// XCD-aware block swizzle (T1).
template<typename OutT>
__global__ __launch_bounds__(256)
void gemm_swz(const unsigned short* __restrict__ A, const unsigned short* __restrict__ B,
              OutT* __restrict__ C, int M, int N, int K, int lda)
{
    __shared__ __align__(16) unsigned short Al[128][64];
    __shared__ __align__(16) unsigned short Bl[128][64];
    const int tid  = threadIdx.x;
    const int lane = tid & 63;
    const int w    = tid >> 6;
    const int wr   = w >> 1, wc = w & 1;
    const int l16  = lane & 15, l4 = lane >> 4;
    const int nwg  = gridDim.x * gridDim.y;
    const int id   = blockIdx.y * gridDim.x + blockIdx.x;
    const int swz  = (id & 7) * (nwg >> 3) + (id >> 3);
    const int bx   = swz % gridDim.x, by = swz / gridDim.x;
    const int tm   = by * 128, tn = bx * 128;
    const int srow  = lane >> 3;
    const int sslot = (lane & 7) ^ srow;

    f32x4 acc[4][4] = {};

    for (int ko = 0; ko < K; ko += 64) {
        __syncthreads();
#pragma unroll
        for (int it = 0; it < 4; ++it) {
            int ca = w * 4 + it;
            int row = ca * 8 + srow;
            g2lds16(&A[(size_t)(tm + row) * lda + ko + sslot * 8], &Al[ca * 8][0]);
            g2lds16(&B[(size_t)(tn + row) * K   + ko + sslot * 8], &Bl[ca * 8][0]);
        }
        __syncthreads();
#pragma unroll
        for (int kk = 0; kk < 2; ++kk) {
            const int rslot = (kk * 4 + l4) ^ (l16 & 7);
            bf16x8 af[4], bfr[4];
#pragma unroll
            for (int i = 0; i < 4; ++i)
                af[i] = *(const bf16x8_a*)&Al[wr*64 + i*16 + l16][rslot * 8];
#pragma unroll
            for (int j = 0; j < 4; ++j)
                bfr[j] = *(const bf16x8_a*)&Bl[wc*64 + j*16 + l16][rslot * 8];
#pragma unroll
            for (int i = 0; i < 4; ++i)
#pragma unroll
                for (int j = 0; j < 4; ++j)
                    acc[i][j] = __builtin_amdgcn_mfma_f32_16x16x32_bf16(af[i], bfr[j], acc[i][j], 0, 0, 0);
        }
    }
#pragma unroll
    for (int i = 0; i < 4; ++i)
#pragma unroll
        for (int j = 0; j < 4; ++j)
#pragma unroll
            for (int r = 0; r < 4; ++r) {
                int row = tm + wr*64 + i*16 + l4*4 + r;
                int col = tn + wc*64 + j*16 + l16;
                if constexpr (std::is_same<OutT, float>::value)
                    C[(size_t)row * N + col] = acc[i][j][r];
                else
                    C[(size_t)row * N + col] = f2bf(acc[i][j][r]);
            }
}

// Fallback GEMM (reg-staged padded LDS, f32 or bf16 operands).
template<bool A_BF16, bool B_BF16, typename OutT>
__global__ __launch_bounds__(256)
void gemm_bt(const void* __restrict__ Av, const void* __restrict__ Bv,
             OutT* __restrict__ C, int M, int N, int K, int lda)
{
    __shared__ __align__(16) unsigned short Al[128][72];
    __shared__ __align__(16) unsigned short Bl[128][72];
    const int tid  = threadIdx.x;
    const int lane = tid & 63;
    const int w    = tid >> 6;
    const int wr   = w >> 1, wc = w & 1;
    const int l16  = lane & 15, l4 = lane >> 4;
    const int tm   = blockIdx.y * 128, tn = blockIdx.x * 128;

    f32x4 acc[4][4] = {};

    for (int ko = 0; ko < K; ko += 64) {
        __syncthreads();
#pragma unroll
        for (int it = 0; it < 4; ++it) {
            int c = tid + 256 * it;
            int row = c >> 3, col0 = (c & 7) * 8;
            if constexpr (A_BF16) {
                const unsigned short* A = (const unsigned short*)Av;
                *(u16x8_a*)&Al[row][col0] =
                    *(const u16x8_a*)&A[(size_t)(tm + row) * lda + ko + col0];
            } else {
                const float* A = (const float*)Av;
                const float* p = &A[(size_t)(tm + row) * lda + ko + col0];
                float4 d0 = *(const float4_a*)p;
                float4 d1 = *(const float4_a*)(p + 4);
                u16x8 t;
                t[0] = f2bf(d0.x); t[1] = f2bf(d0.y); t[2] = f2bf(d0.z); t[3] = f2bf(d0.w);
                t[4] = f2bf(d1.x); t[5] = f2bf(d1.y); t[6] = f2bf(d1.z); t[7] = f2bf(d1.w);
                *(u16x8_a*)&Al[row][col0] = t;
            }
            if constexpr (B_BF16) {
                const unsigned short* B = (const unsigned short*)Bv;
                *(u16x8_a*)&Bl[row][col0] =
                    *(const u16x8_a*)&B[(size_t)(tn + row) * K + ko + col0];
            } else {
                const float* B = (const float*)Bv;
                const float* p = &B[(size_t)(tn + row) * K + ko + col0];
                float4 d0 = *(const float4_a*)p;
                float4 d1 = *(const float4_a*)(p + 4);
                u16x8 t;
                t[0] = f2bf(d0.x); t[1] = f2bf(d0.y); t[2] = f2bf(d0.z); t[3] = f2bf(d0.w);
                t[4] = f2bf(d1.x); t[5] = f2bf(d1.y); t[6] = f2bf(d1.z); t[7] = f2bf(d1.w);
                *(u16x8_a*)&Bl[row][col0] = t;
            }
        }
        __syncthreads();
#pragma unroll
        for (int kk = 0; kk < 2; ++kk) {
            bf16x8 af[4], bfr[4];
#pragma unroll
            for (int i = 0; i < 4; ++i)
                af[i] = *(const bf16x8_a*)&Al[wr*64 + i*16 + l16][kk*32 + l4*8];
#pragma unroll
            for (int j = 0; j < 4; ++j)
                bfr[j] = *(const bf16x8_a*)&Bl[wc*64 + j*16 + l16][kk*32 + l4*8];
#pragma unroll
            for (int i = 0; i < 4; ++i)
#pragma unroll
                for (int j = 0; j < 4; ++j)
                    acc[i][j] = __builtin_amdgcn_mfma_f32_16x16x32_bf16(af[i], bfr[j], acc[i][j], 0, 0, 0);
        }
    }
#pragma unroll
    for (int i = 0; i < 4; ++i)
#pragma unroll
        for (int j = 0; j < 4; ++j)
#pragma unroll
            for (int r = 0; r < 4; ++r) {
                int row = tm + wr*64 + i*16 + l4*4 + r;
                int col = tn + wc*64 + j*16 + l16;
                if constexpr (std::is_same<OutT, float>::value)
                    C[(size_t)row * N + col] = acc[i][j][r];
                else
                    C[(size_t)row * N + col] = f2bf(acc[i][j][r]);
            }
}

// In-place RoPE, trig-deduplicated. Row stride RS. grid = B*SEQ*16/256.
template<int NH>
__global__ __launch_bounds__(256)
void rope_kernel(unsigned short* __restrict__ X, const int* __restrict__ pos_ids, int RS)
{
    int c = blockIdx.x * 256 + threadIdx.x;
    int d0 = (c & 15) * 8;
    int l  = (c >> 4) & 4095;
    int b  = c >> 16;
    int pos = pos_ids[b * SEQ + l];
    float sth[4], cth[4];
#pragma unroll
    for (int j = 0; j < 4; ++j) {
        int i = (d0 >> 1) + j;
        float invf = powf(10000.0f, -(float)i * (1.0f / 64.0f));
        float ang = (float)pos * invf;
        sincosf(ang, &sth[j], &cth[j]);
    }
    size_t base = (size_t)(b * SEQ + l) * RS + d0;
#pragma unroll
    for (int h = 0; h < NH; ++h) {
        u16x8 d = *(const u16x8_a*)&X[base + h * HDIM];
#pragma unroll
        for (int j = 0; j < 4; ++j) {
            float x0 = bf2f(d[2*j]), x1 = bf2f(d[2*j+1]);
            d[2*j]   = f2bf(x0 * cth[j] - x1 * sth[j]);
            d[2*j+1] = f2bf(x0 * sth[j] + x1 * cth[j]);
        }
        *(u16x8_a*)&X[base + h * HDIM] = d;
    }
}

// Flash attention (r19-exact, the measured-best variant): BLOCK-causal +
// segment mask + skip + uniform-mask fast path; swapped QK^T; in-reg P
// (cvt_pk + permlane32_swap); reg-prefetched K/V; LDS double-buffer, one
// barrier per tile, staging writes AFTER compute (r20's mid-compute write
// placement and setprio both regressed — reverted).
// O aliases Q (in-place). launch_bounds(256,2): must not spill (r14 lesson).
__global__ __launch_bounds__(256, 2)
void attn_kernel(const unsigned short* Q,
                 const unsigned short* K,
                 const unsigned short* V,
                 const int* __restrict__ seg,
                 unsigned short* O, int RS)
{
    __shared__ __align__(16) unsigned short Kl[2][64][136];
    __shared__ __align__(16) unsigned short Vt[2][128][72];

    const int tid  = threadIdx.x;
    const int lane = tid & 63;
    const int l32  = lane & 31, hi = lane >> 5;
    const int w    = tid >> 6;
    const int qt = (SEQ / 128 - 1) - blockIdx.x;
    const int h  = blockIdx.y;
    const int b  = blockIdx.z;
    const int qg0 = qt * 128 + w * 32;
    const int hoff = h * HDIM;

    bf16x8 qf[8];
    {
        size_t base = (size_t)(b * SEQ + qg0 + l32) * RS + hoff;
#pragma unroll
        for (int kk = 0; kk < 8; ++kk)
            qf[kk] = *(const bf16x8_a*)&Q[base + kk*16 + hi*8];
    }

    f32x16 acco0 = {}, acco1 = {}, acco2 = {}, acco3 = {};
    float lsum = 0.f;

    const int nkt = ((qt >> 4) + 1) * 32;

    int lo = 0, hb = SEQ;
    while (lo < hb) { int mid = (lo + hb) >> 1; if (seg[b * SEQ + mid] == 0) lo = mid + 1; else hb = mid; }
    const int boundary = lo;
    const bool blk_seg1 = (seg[b * SEQ + qt * 128] == 1);
    const bool blk_seg0 = (seg[b * SEQ + qt * 128 + 127] == 0);
    const bool mixed = !blk_seg0 && !blk_seg1;
    int kstart = 0, kend = nkt;
    if (blk_seg1) kstart = boundary >> 6;
    if (blk_seg0) {
        int ke = (boundary + 63) >> 6;
        kend = ke < nkt ? ke : nkt;
    }
    const bool qlt = (qg0 + l32) < boundary;

    const int kp = tid & 31, db = tid >> 5;
    const float sc = 0.08838834764831845f;

    // ---- prefetch regs for tile kstart ----
    u16x8 kreg[4], v0a, v0b, v1a, v1b;
    {
        const int kb = kstart * 64;
#pragma unroll
        for (int it = 0; it < 4; ++it) {
            int c = tid + 256 * it;
            kreg[it] = *(const u16x8_a*)&K[(size_t)(b * SEQ + kb + (c >> 4)) * RS + hoff + (c & 15) * 8];
        }
        size_t vb0 = (size_t)(b * SEQ + kb + 2 * kp) * RS + hoff + db * 16;
        size_t vb1 = (size_t)(b * SEQ + kb + 2 * kp + 1) * RS + hoff + db * 16;
        v0a = *(const u16x8_a*)&V[vb0];     v0b = *(const u16x8_a*)&V[vb0 + 8];
        v1a = *(const u16x8_a*)&V[vb1];     v1b = *(const u16x8_a*)&V[vb1 + 8];
    }
    // ---- prologue: write tile kstart -> buffer 0; issue loads kstart+1 ----
#pragma unroll
    for (int it = 0; it < 4; ++it) {
        int c = tid + 256 * it;
        *(u16x8_a*)&Kl[0][c >> 4][(c & 15) * 8] = kreg[it];
    }
#pragma unroll
    for (int j = 0; j < 8; ++j) {
        *(u32_a*)&Vt[0][db * 16 + j][2 * kp] =
            (unsigned int)(unsigned short)v0a[j] | ((unsigned int)(unsigned short)v1a[j] << 16);
        *(u32_a*)&Vt[0][db * 16 + 8 + j][2 * kp] =
            (unsigned int)(unsigned short)v0b[j] | ((unsigned int)(unsigned short)v1b[j] << 16);
    }
    if (kstart + 1 < kend) {
        const int kb2 = (kstart + 1) * 64;
#pragma unroll
        for (int it = 0; it < 4; ++it) {
            int c = tid + 256 * it;
            kreg[it] = *(const u16x8_a*)&K[(size_t)(b * SEQ + kb2 + (c >> 4)) * RS + hoff + (c & 15) * 8];
        }
        size_t vb0 = (size_t)(b * SEQ + kb2 + 2 * kp) * RS + hoff + db * 16;
        size_t vb1 = (size_t)(b * SEQ + kb2 + 2 * kp + 1) * RS + hoff + db * 16;
        v0a = *(const u16x8_a*)&V[vb0];     v0b = *(const u16x8_a*)&V[vb0 + 8];
        v1a = *(const u16x8_a*)&V[vb1];     v1b = *(const u16x8_a*)&V[vb1 + 8];
    }
    __syncthreads();

    int buf = 0;
    for (int kt = kstart; kt < kend; ++kt) {
        const int kb = kt * 64;

        // ---- compute tile kt from LDS[buf] ----
        f32x16 a0 = {}, a1 = {};
#pragma unroll
        for (int kk = 0; kk < 8; ++kk) {
            bf16x8 k0 = *(const bf16x8_a*)&Kl[buf][     l32][kk*16 + hi*8];
            bf16x8 k1 = *(const bf16x8_a*)&Kl[buf][32 + l32][kk*16 + hi*8];
            a0 = __builtin_amdgcn_mfma_f32_32x32x16_bf16(k0, qf[kk], a0, 0, 0, 0);
            a1 = __builtin_amdgcn_mfma_f32_32x32x16_bf16(k1, qf[kk], a1, 0, 0, 0);
        }

        unsigned int pk0[8], pk1[8];
        const bool need_mask = mixed || (kb < boundary && kb + 64 > boundary);
        if (need_mask) {
            const int kb0 = kb + 4 * hi, kb1 = kb + 32 + 4 * hi;
#pragma unroll
            for (int i = 0; i < 8; ++i) {
                int r0 = 2 * i;
                int off = (r0 & 3) + 8 * (r0 >> 2);
                float p0 = ((kb0 + off     < boundary) == qlt) ? __expf(a0[r0]     * sc) : 0.0f;
                float p1 = ((kb0 + off + 1 < boundary) == qlt) ? __expf(a0[r0 + 1] * sc) : 0.0f;
                float q0 = ((kb1 + off     < boundary) == qlt) ? __expf(a1[r0]     * sc) : 0.0f;
                float q1 = ((kb1 + off + 1 < boundary) == qlt) ? __expf(a1[r0 + 1] * sc) : 0.0f;
                lsum += (p0 + p1) + (q0 + q1);
                pk0[i] = cvt_pk(p0, p1);
                pk1[i] = cvt_pk(q0, q1);
            }
        } else {
#pragma unroll
            for (int i = 0; i < 8; ++i) {
                int r0 = 2 * i;
                float p0 = __expf(a0[r0]     * sc);
                float p1 = __expf(a0[r0 + 1] * sc);
                float q0 = __expf(a1[r0]     * sc);
                float q1 = __expf(a1[r0 + 1] * sc);
                lsum += (p0 + p1) + (q0 + q1);
                pk0[i] = cvt_pk(p0, p1);
                pk1[i] = cvt_pk(q0, q1);
            }
        }
        plane_swap(pk0[0], pk0[2]); plane_swap(pk0[1], pk0[3]);
        plane_swap(pk0[4], pk0[6]); plane_swap(pk0[5], pk0[7]);
        plane_swap(pk1[0], pk1[2]); plane_swap(pk1[1], pk1[3]);
        plane_swap(pk1[4], pk1[6]); plane_swap(pk1[5], pk1[7]);
        bf16x8 pf[4];
        pf[0] = pack4(pk0[0], pk0[1], pk0[2], pk0[3]);
        pf[1] = pack4(pk0[4], pk0[5], pk0[6], pk0[7]);
        pf[2] = pack4(pk1[0], pk1[1], pk1[2], pk1[3]);
        pf[3] = pack4(pk1[4], pk1[5], pk1[6], pk1[7]);

#pragma unroll
        for (int ks = 0; ks < 4; ++ks) {
            bf16x8 vf0 = *(const bf16x8_a*)&Vt[buf][      l32][ks*16 + hi*8];
            bf16x8 vf1 = *(const bf16x8_a*)&Vt[buf][32  + l32][ks*16 + hi*8];
            bf16x8 vf2 = *(const bf16x8_a*)&Vt[buf][64  + l32][ks*16 + hi*8];
            bf16x8 vf3 = *(const bf16x8_a*)&Vt[buf][96  + l32][ks*16 + hi*8];
            acco0 = __builtin_amdgcn_mfma_f32_32x32x16_bf16(pf[ks], vf0, acco0, 0, 0, 0);
            acco1 = __builtin_amdgcn_mfma_f32_32x32x16_bf16(pf[ks], vf1, acco1, 0, 0, 0);
            acco2 = __builtin_amdgcn_mfma_f32_32x32x16_bf16(pf[ks], vf2, acco2, 0, 0, 0);
            acco3 = __builtin_amdgcn_mfma_f32_32x32x16_bf16(pf[ks], vf3, acco3, 0, 0, 0);
        }

        // ---- write tile kt+1 -> LDS[buf^1]; issue loads kt+2; one barrier ----
        if (kt + 1 < kend) {
            const int nb = buf ^ 1;
#pragma unroll
            for (int it = 0; it < 4; ++it) {
                int c = tid + 256 * it;
                *(u16x8_a*)&Kl[nb][c >> 4][(c & 15) * 8] = kreg[it];
            }
#pragma unroll
            for (int j = 0; j < 8; ++j) {
                *(u32_a*)&Vt[nb][db * 16 + j][2 * kp] =
                    (unsigned int)(unsigned short)v0a[j] | ((unsigned int)(unsigned short)v1a[j] << 16);
                *(u32_a*)&Vt[nb][db * 16 + 8 + j][2 * kp] =
                    (unsigned int)(unsigned short)v0b[j] | ((unsigned int)(unsigned short)v1b[j] << 16);
            }
            if (kt + 2 < kend) {
                const int kb2 = (kt + 2) * 64;
#pragma unroll
                for (int it = 0; it < 4; ++it) {
                    int c = tid + 256 * it;
                    kreg[it] = *(const u16x8_a*)&K[(size_t)(b * SEQ + kb2 + (c >> 4)) * RS + hoff + (c & 15) * 8];
                }
                size_t vb0 = (size_t)(b * SEQ + kb2 + 2 * kp) * RS + hoff + db * 16;
                size_t vb1 = (size_t)(b * SEQ + kb2 + 2 * kp + 1) * RS + hoff + db * 16;
                v0a = *(const u16x8_a*)&V[vb0];     v0b = *(const u16x8_a*)&V[vb0 + 8];
                v1a = *(const u16x8_a*)&V[vb1];     v1b = *(const u16x8_a*)&V[vb1 + 8];
            }
            __syncthreads();
        }
        buf ^= 1;
    }

    // ---- epilogue ----
    float tot = lsum + __shfl_xor(lsum, 32, 64);
#pragma unroll
    for (int r = 0; r < 16; ++r) {
        int qrow = (r & 3) + 8 * (r >> 2) + 4 * hi;
        float inv = 1.0f / __shfl(tot, qrow, 64);
        size_t base = (size_t)(b * SEQ + qg0 + qrow) * RS + hoff;
        O[base +       l32] = f2bf(acco0[r] * inv);
        O[base +  32 + l32] = f2bf(acco1[r] * inv);
        O[base +  64 + l32] = f2bf(acco2[r] * inv);
        O[base +  96 + l32] = f2bf(acco3[r] * inv);
    }
}

extern "C" void kernel_launch(void* const* d_in, const int* in_sizes, int n_in,
                              void* d_out, int out_size, void* d_ws, size_t ws_size,
                              hipStream_t stream)
{
    const float* X  = (const float*)d_in[0];
    const float* wq = (const float*)d_in[1];
    const float* wk = (const float*)d_in[2];
    const float* wv = (const float*)d_in[3];
    const float* wo = (const float*)d_in[4];
    const int* seg = (const int*)d_in[n_in - 2];
    const int* pos = (const int*)d_in[n_in - 1];
    float* out = (float*)d_out;

    const size_t NTOK = (size_t)BATCH * SEQ;        // 8192
    const size_t MAT  = NTOK * HID;                 // 8.39M elems
    const size_t WSZ  = (size_t)HID * HID;          // 1.05M elems

    if (ws_size >= (4 * MAT + 4 * WSZ) * sizeof(unsigned short)) {
        unsigned short* QKVb = (unsigned short*)d_ws;              // 3*MAT
        unsigned short* Xb   = QKVb + 3 * MAT;                     // MAT
        unsigned short* Wb   = Xb + MAT;                           // 4*WSZ
        unsigned short* Wob  = Wb + 3 * WSZ;

        cvt_kernel<<<(int)(MAT / (256 * 8)), 256, 0, stream>>>(X, Xb);
        cvtw_kernel<<<(int)(4 * WSZ / (256 * 8)), 256, 0, stream>>>(wq, wk, wv, wo, Wb);

        dim3 gq(3 * HID / 128, (int)(NTOK / 128));   // (24, 64) -> 1536 blocks
        gemm_swz<unsigned short><<<gq, 256, 0, stream>>>(
            Xb, Wb, QKVb, (int)NTOK, 3 * HID, HID, HID);

        rope_kernel<16><<<(BATCH * SEQ * 16) / 256, 256, 0, stream>>>(QKVb, pos, 3 * HID);

        dim3 ga(SEQ / 128, HEADS, BATCH);
        attn_kernel<<<ga, 256, 0, stream>>>(QKVb, QKVb + HID, QKVb + 2 * HID, seg,
                                            QKVb /* in-place into Q slots */, 3 * HID);

        dim3 go(HID / 128, (int)(NTOK / 128));       // (8, 64) -> 512 blocks
        gemm_swz<float><<<go, 256, 0, stream>>>(
            QKVb, Wob, out, (int)NTOK, HID, HID, 3 * HID);
    } else {
        unsigned short* Qb = (unsigned short*)d_ws;
        unsigned short* Kb = Qb + MAT;
        unsigned short* Vb = Kb + MAT;

        dim3 gg(HID / 128, (int)(NTOK / 128));
        gemm_bt<false, false, unsigned short><<<gg, 256, 0, stream>>>(
            (const void*)X, (const void*)wq, Qb, (int)NTOK, HID, HID, HID);
        gemm_bt<false, false, unsigned short><<<gg, 256, 0, stream>>>(
            (const void*)X, (const void*)wk, Kb, (int)NTOK, HID, HID, HID);
        gemm_bt<false, false, unsigned short><<<gg, 256, 0, stream>>>(
            (const void*)X, (const void*)wv, Vb, (int)NTOK, HID, HID, HID);

        rope_kernel<8><<<(BATCH * SEQ * 16) / 256, 256, 0, stream>>>(Qb, pos, HID);
        rope_kernel<8><<<(BATCH * SEQ * 16) / 256, 256, 0, stream>>>(Kb, pos, HID);

        dim3 ga(SEQ / 128, HEADS, BATCH);
        attn_kernel<<<ga, 256, 0, stream>>>(Qb, Kb, Vb, seg, Qb, HID);

        gemm_bt<true, false, float><<<gg, 256, 0, stream>>>(
            (const void*)Qb, (const void*)wo, out, (int)NTOK, HID, HID, HID);
    }
}